// Round 6
// baseline (1374.972 us; speedup 1.0000x reference)
//
#include <hip/hip_runtime.h>
#include <math.h>

#define B_  32
#define H_  8
#define DM_ 512
#define DI_ 2048

typedef unsigned short u16;
typedef short s16x8 __attribute__((ext_vector_type(8)));
typedef short s16x4 __attribute__((ext_vector_type(4)));
typedef float f32x4 __attribute__((ext_vector_type(4)));

__device__ __forceinline__ float b2f(u16 u) {
  return __uint_as_float(((unsigned)u) << 16);
}
__device__ __forceinline__ u16 f2b(float f) {           // RNE f32 -> bf16
  unsigned u = __float_as_uint(f);
  return (u16)((u + 0x7fffu + ((u >> 16) & 1u)) >> 16);
}

// ---------------------------------------------------------------------------
// MFMA bf16 GEMM with f32 or bf16 operands (converted at LDS staging).
//   C[M,N] = A[M,K] @ W[N,K]^T + bias[N]  (+ epilogue)
// ADT : A dtype 0=f32, 1=bf16.  W,bias always f32 (from d_in).
// EPI : 0 none, 1 relu, 2 +residual.  RDT: residual dtype 0=f32, 1=bf16.
// OUTF: 1 bf16 out, 0 f32 out.
// 128x128 tile, BK=64, 256 thr = 4 waves, wave = 64x64 (4x4 x 16x16x32 MFMA).
// LDS [row][k] stride 72 shorts. A/B frags share the (lane>>4)*8+j k-mapping
// (any shared bijection is valid). C/D: col=lane&15, row=(lane>>4)*4+reg.
// ---------------------------------------------------------------------------
template<int ADT, int EPI, int RDT, int OUTF>
__global__ __launch_bounds__(256)
void gemm_mfma(const void* __restrict__ Av, const float* __restrict__ W,
               const float* __restrict__ bias, const void* __restrict__ Rv,
               void* __restrict__ Cout, int M, int N, int K)
{
  __shared__ u16 As[128 * 72];
  __shared__ u16 Bs[128 * 72];
  const int t = threadIdx.x;
  const int bm = blockIdx.y * 128, bn = blockIdx.x * 128;
  const int lane = t & 63, wave = t >> 6;
  const int lr = lane & 15, kg = lane >> 4;
  const int wr = wave >> 1, wc = wave & 1;
  const int srow = t >> 3, schk = (t & 7) * 8;

  f32x4 acc[4][4] = {};

  for (int k0 = 0; k0 < K; k0 += 64) {
#pragma unroll
    for (int p = 0; p < 4; p++) {
      const int r = srow + p * 32;
      s16x8 av = {};
      if (bm + r < M) {
        if (ADT == 0) {
          const float* ap = (const float*)Av + (size_t)(bm + r) * K + k0 + schk;
          const float4 a0 = *(const float4*)ap;
          const float4 a1 = *(const float4*)(ap + 4);
          av[0] = (short)f2b(a0.x); av[1] = (short)f2b(a0.y);
          av[2] = (short)f2b(a0.z); av[3] = (short)f2b(a0.w);
          av[4] = (short)f2b(a1.x); av[5] = (short)f2b(a1.y);
          av[6] = (short)f2b(a1.z); av[7] = (short)f2b(a1.w);
        } else {
          av = *(const s16x8*)((const u16*)Av + (size_t)(bm + r) * K + k0 + schk);
        }
      }
      *(s16x8*)&As[r * 72 + schk] = av;
      const float* wp = W + (size_t)(bn + r) * K + k0 + schk;  // N%128==0: in-range
      const float4 w0 = *(const float4*)wp;
      const float4 w1 = *(const float4*)(wp + 4);
      s16x8 wv;
      wv[0] = (short)f2b(w0.x); wv[1] = (short)f2b(w0.y);
      wv[2] = (short)f2b(w0.z); wv[3] = (short)f2b(w0.w);
      wv[4] = (short)f2b(w1.x); wv[5] = (short)f2b(w1.y);
      wv[6] = (short)f2b(w1.z); wv[7] = (short)f2b(w1.w);
      *(s16x8*)&Bs[r * 72 + schk] = wv;
    }
    __syncthreads();
#pragma unroll
    for (int ks = 0; ks < 2; ks++) {
      s16x8 af[4], bg[4];
#pragma unroll
      for (int m = 0; m < 4; m++)
        af[m] = *(const s16x8*)&As[(wr * 64 + m * 16 + lr) * 72 + ks * 32 + kg * 8];
#pragma unroll
      for (int n = 0; n < 4; n++)
        bg[n] = *(const s16x8*)&Bs[(wc * 64 + n * 16 + lr) * 72 + ks * 32 + kg * 8];
#pragma unroll
      for (int m = 0; m < 4; m++)
#pragma unroll
        for (int n = 0; n < 4; n++)
          acc[m][n] = __builtin_amdgcn_mfma_f32_16x16x32_bf16(af[m], bg[n], acc[m][n], 0, 0, 0);
    }
    __syncthreads();
  }

  float bv[4];
#pragma unroll
  for (int n = 0; n < 4; n++) bv[n] = bias[bn + wc * 64 + n * 16 + lr];
#pragma unroll
  for (int m = 0; m < 4; m++) {
#pragma unroll
    for (int j = 0; j < 4; j++) {
      const int row = bm + wr * 64 + m * 16 + kg * 4 + j;
      if (row >= M) continue;
#pragma unroll
      for (int n = 0; n < 4; n++) {
        const int col = bn + wc * 64 + n * 16 + lr;
        float x = acc[m][n][j] + bv[n];
        if (EPI == 1) x = fmaxf(x, 0.f);
        if (EPI == 2) {
          if (RDT == 0) x += ((const float*)Rv)[(size_t)row * N + col];
          else          x += b2f(((const u16*)Rv)[(size_t)row * N + col]);
        }
        if (OUTF) ((u16*)Cout)[(size_t)row * N + col] = f2b(x);
        else      ((float*)Cout)[(size_t)row * N + col] = x;
      }
    }
  }
}

// ---------------------------------------------------------------------------
// Attention: one block (256 thr = 4 waves) = 16 q-rows of one (b,h).
// Q/K/V bf16 (B,L,H*64) row-major; K/V tiles staged in LDS (coalesced).
// Each wave owns 4 q-rows. QK: lane = edge j. PV: lane = feature d.
// f32 online softmax, finite sentinels only (no +-inf anywhere).
// mask is INT32 (harness uploads bools as int32): nonzero = masked out.
// ---------------------------------------------------------------------------
__global__ __launch_bounds__(256)
void attn_kernel(const u16* __restrict__ Q, const u16* __restrict__ K,
                 const u16* __restrict__ V, const int* __restrict__ mask,
                 u16* __restrict__ ctxb, int Lq, int Lv)
{
  __shared__ u16 Ks[64][68];
  __shared__ u16 Vs[64][68];
  const float SENT = -1e30f;
  const int qt = blockIdx.x, h = blockIdx.y, b = blockIdx.z;
  const int t = threadIdx.x;
  const int wave = t >> 6, lane = t & 63;
  const int q0 = qt * 16 + wave * 4;

  float qv[4], mx[4], ln[4], ctx[4];
  const int* mrow[4];
#pragma unroll
  for (int i = 0; i < 4; i++) {
    const int qi = min(q0 + i, Lq - 1);
    qv[i] = b2f(Q[(((size_t)b * Lq + qi) * H_ + h) * 64 + lane]);
    mrow[i] = mask + ((size_t)b * Lq + qi) * (size_t)Lv;
    mx[i] = SENT; ln[i] = 0.f; ctx[i] = 0.f;
  }

  const int jrow = t >> 2, cs = (t & 3) * 16;
  const size_t kvbase = (size_t)b * Lv * DM_ + h * 64;

  for (int j0 = 0; j0 < Lv; j0 += 64) {
    __syncthreads();
    if (j0 + jrow < Lv) {
      const u16* kp = K + kvbase + (size_t)(j0 + jrow) * DM_ + cs;
      const u16* vp = V + kvbase + (size_t)(j0 + jrow) * DM_ + cs;
#pragma unroll
      for (int c = 0; c < 16; c += 4) {
        *(s16x4*)&Ks[jrow][cs + c] = *(const s16x4*)(kp + c);
        *(s16x4*)&Vs[jrow][cs + c] = *(const s16x4*)(vp + c);
      }
    } else {
      const s16x4 z = {};
#pragma unroll
      for (int c = 0; c < 16; c += 4) {
        *(s16x4*)&Ks[jrow][cs + c] = z;
        *(s16x4*)&Vs[jrow][cs + c] = z;
      }
    }
    __syncthreads();

    const int j = j0 + lane;
    const int jc = min(j, Lv - 1);
    float s[4] = {0.f, 0.f, 0.f, 0.f};
#pragma unroll
    for (int d = 0; d < 64; d++) {
      const float kvf = b2f(Ks[lane][d]);
#pragma unroll
      for (int i = 0; i < 4; i++) s[i] = fmaf(__shfl(qv[i], d), kvf, s[i]);
    }
    float p[4];
#pragma unroll
    for (int i = 0; i < 4; i++) {
      const bool dead = (j >= Lv) || (mrow[i][jc] != 0);
      const float si = dead ? SENT : s[i] * 0.125f;
      float gm = si;
#pragma unroll
      for (int o = 32; o; o >>= 1) gm = fmaxf(gm, __shfl_xor(gm, o));
      if (gm > -1e29f) {
        const float mn = fmaxf(mx[i], gm);
        const float sc = __expf(mx[i] - mn);
        const float pi = __expf(si - mn);
        float gs = pi;
#pragma unroll
        for (int o = 32; o; o >>= 1) gs += __shfl_xor(gs, o);
        ln[i] = ln[i] * sc + gs;
        ctx[i] *= sc;
        mx[i] = mn;
        p[i] = pi;
      } else {
        p[i] = 0.f;
      }
    }

    const int jlim = min(64, Lv - j0);
    for (int jj = 0; jj < jlim; jj++) {
      const float vv = b2f(Vs[jj][lane]);
#pragma unroll
      for (int i = 0; i < 4; i++) ctx[i] = fmaf(__shfl(p[i], jj), vv, ctx[i]);
    }
  }

#pragma unroll
  for (int i = 0; i < 4; i++) {
    if (q0 + i < Lq) {
      const float inv = ln[i] > 0.f ? 1.f / ln[i] : 0.f;
      ctxb[(((size_t)b * Lq + q0 + i) * H_ + h) * 64 + lane] = f2b(ctx[i] * inv);
    }
  }
}

// ---------------------------------------------------------------------------
// Row LayerNorm (D=512, f32 in, f32 g/b) + non-pad mask (int32).
// OUTF: 1 bf16, 0 f32. In-place (Y==X) safe for OUTF=0.
// ---------------------------------------------------------------------------
template<int OUTF>
__global__ __launch_bounds__(256)
void ln_mask_kernel(const float* __restrict__ X, const float* __restrict__ g,
                    const float* __restrict__ bta, const int* __restrict__ npm,
                    void* __restrict__ Y)
{
  __shared__ float sm[8];
  const int row = blockIdx.x;
  const int t = threadIdx.x;
  const float2 x = *(const float2*)&X[(size_t)row * DM_ + t * 2];

  float s = x.x + x.y;
#pragma unroll
  for (int o = 32; o; o >>= 1) s += __shfl_xor(s, o);
  if ((t & 63) == 0) sm[t >> 6] = s;
  __syncthreads();
  const float mean = (sm[0] + sm[1] + sm[2] + sm[3]) * (1.f / DM_);

  const float d0 = x.x - mean, d1 = x.y - mean;
  float vs = d0 * d0 + d1 * d1;
#pragma unroll
  for (int o = 32; o; o >>= 1) vs += __shfl_xor(vs, o);
  if ((t & 63) == 0) sm[4 + (t >> 6)] = vs;
  __syncthreads();
  const float var = (sm[4] + sm[5] + sm[6] + sm[7]) * (1.f / DM_);

  const float inv = rsqrtf(var + 1e-5f);
  const float np = npm[row] ? 1.f : 0.f;
  const int c = t * 2;
  const float y0 = (d0 * inv * g[c]     + bta[c])     * np;
  const float y1 = (d1 * inv * g[c + 1] + bta[c + 1]) * np;
  if (OUTF) {
    const unsigned pair = (unsigned)f2b(y0) | ((unsigned)f2b(y1) << 16);
    *(unsigned*)((u16*)Y + (size_t)row * DM_ + c) = pair;
  } else {
    *(float2*)((float*)Y + (size_t)row * DM_ + c) = make_float2(y0, y1);
  }
}

// ---------------------------------------------------------------------------
// Gather valid rows (f32): out[i][:] = F[gather_idx[i]][:]
// ---------------------------------------------------------------------------
__global__ __launch_bounds__(128)
void gather_kernel(const float* __restrict__ F, const int* __restrict__ idx,
                   float* __restrict__ out)
{
  const int i = blockIdx.x;
  const int t = threadIdx.x;           // 128 threads x float4 = 512
  const int r = idx[i];
  *(float4*)&out[(size_t)i * DM_ + t * 4] =
      *(const float4*)&F[(size_t)r * DM_ + t * 4];
}

// ---------------------------------------------------------------------------
extern "C" void kernel_launch(void* const* d_in, const int* in_sizes, int n_in,
                              void* d_out, int out_size, void* d_ws, size_t ws_size,
                              hipStream_t stream)
{
  const float* entity = (const float*)d_in[0];
  const float* pred   = (const float*)d_in[1];
  const float* w_qs = (const float*)d_in[2];
  const float* b_qs = (const float*)d_in[3];
  const float* w_ks = (const float*)d_in[4];
  const float* b_ks = (const float*)d_in[5];
  const float* w_vs = (const float*)d_in[6];
  const float* b_vs = (const float*)d_in[7];
  const float* w_fc = (const float*)d_in[8];
  const float* b_fc = (const float*)d_in[9];
  const float* ln1g = (const float*)d_in[10];
  const float* ln1b = (const float*)d_in[11];
  const float* w1   = (const float*)d_in[12];
  const float* b1   = (const float*)d_in[13];
  const float* w2   = (const float*)d_in[14];
  const float* b2   = (const float*)d_in[15];
  const float* ln2g = (const float*)d_in[16];
  const float* ln2b = (const float*)d_in[17];
  const int* amask = (const int*)d_in[18];   // int32 bools (harness convention)
  const int* npm   = (const int*)d_in[19];   // int32 bools
  const int* gidx  = (const int*)d_in[20];

  const int Lq = in_sizes[0] / (B_ * DM_);
  const int Lv = in_sizes[1] / (B_ * DM_);
  const int nValid = in_sizes[20];
  const int Mq = B_ * Lq, Mv = B_ * Lv;

  // Workspace: 4 regions, strict lifetime reuse (~52.4 MB; proven fit in r4).
  auto algn = [](size_t x) { return (x + 255) & ~(size_t)255; };
  const size_t bKV  = (size_t)Mv * DM_ * 2;   // bf16 K or V
  const size_t bTMP = (size_t)Mq * DM_ * 4;   // f32 tmp1/tmp2/ffin
  const size_t bH   = (size_t)Mq * DI_ * 2;   // bf16 FFN hidden
  const size_t bQ   = (size_t)Mq * DM_ * 2;   // bf16 Q / out1 / ctx
  const size_t szR1 = algn(bKV > bTMP ? bKV : bTMP);   // Kb -> tmp1 -> tmp2/ffin
  const size_t szR2 = algn(bKV > bH ? bKV : bH);       // Vb -> hb
  const size_t szR3 = algn(bQ);                        // Qb -> out1
  const size_t szR4 = algn(bQ);                        // ctxb
  if (szR1 + szR2 + szR3 + szR4 > ws_size) return;     // tripwire (-> zeros)

  char* base = (char*)d_ws;
  char* R1 = base;
  char* R2 = R1 + szR1;
  char* R3 = R2 + szR2;
  char* R4 = R3 + szR3;

  u16*   Kb   = (u16*)R1;  float* tmp1 = (float*)R1;
  float* tmp2 = (float*)R1; float* ffin = (float*)R1;
  u16*   Vb   = (u16*)R2;  u16* hb = (u16*)R2;
  u16*   Qb   = (u16*)R3;  u16* out1 = (u16*)R3;
  u16*   ctxb = (u16*)R4;

  const dim3 blk(256);
  // Q/K/V projections: f32 A/W -> bf16 out (MFMA)
  gemm_mfma<0, 0, 0, 1><<<dim3(DM_ / 128, (Mq + 127) / 128), blk, 0, stream>>>(
      entity, w_qs, b_qs, nullptr, Qb, Mq, DM_, DM_);
  gemm_mfma<0, 0, 0, 1><<<dim3(DM_ / 128, (Mv + 127) / 128), blk, 0, stream>>>(
      pred, w_ks, b_ks, nullptr, Kb, Mv, DM_, DM_);
  gemm_mfma<0, 0, 0, 1><<<dim3(DM_ / 128, (Mv + 127) / 128), blk, 0, stream>>>(
      pred, w_vs, b_vs, nullptr, Vb, Mv, DM_, DM_);
  // fused masked-softmax cross attention (bf16 in/out)
  attn_kernel<<<dim3((Lq + 15) / 16, H_, B_), blk, 0, stream>>>(
      Qb, Kb, Vb, amask, ctxb, Lq, Lv);
  // fc + residual(entity f32) -> f32 tmp1
  gemm_mfma<1, 2, 0, 0><<<dim3(DM_ / 128, (Mq + 127) / 128), blk, 0, stream>>>(
      ctxb, w_fc, b_fc, entity, tmp1, Mq, DM_, DM_);
  // LN1 + npm -> bf16 out1
  ln_mask_kernel<1><<<dim3(Mq), blk, 0, stream>>>(tmp1, ln1g, ln1b, npm, out1);
  // FFN1 (relu) -> bf16 hb
  gemm_mfma<1, 1, 0, 1><<<dim3(DI_ / 128, (Mq + 127) / 128), blk, 0, stream>>>(
      out1, w1, b1, nullptr, hb, Mq, DI_, DM_);
  // FFN2 + residual(out1 bf16) -> f32 tmp2
  gemm_mfma<1, 2, 1, 0><<<dim3(DM_ / 128, (Mq + 127) / 128), blk, 0, stream>>>(
      hb, w2, b2, out1, tmp2, Mq, DM_, DI_);
  // LN2 + npm -> f32 in-place (ffin == tmp2)
  ln_mask_kernel<0><<<dim3(Mq), blk, 0, stream>>>(tmp2, ln2g, ln2b, npm, ffin);
  // gather valid rows -> f32 d_out
  gather_kernel<<<dim3(nValid), dim3(128), 0, stream>>>(ffin, gidx, (float*)d_out);
}

// Round 9
// 512.896 us; speedup vs baseline: 2.6808x; 2.6808x over previous
//
#include <hip/hip_runtime.h>
#include <math.h>

#define B_  32
#define H_  8
#define DM_ 512
#define DI_ 2048

typedef unsigned short u16;
typedef short s16x8 __attribute__((ext_vector_type(8)));
typedef short s16x4 __attribute__((ext_vector_type(4)));
typedef float f32x4 __attribute__((ext_vector_type(4)));

__device__ __forceinline__ float b2f(u16 u) {
  return __uint_as_float(((unsigned)u) << 16);
}
__device__ __forceinline__ u16 f2b(float f) {           // RNE f32 -> bf16
  unsigned u = __float_as_uint(f);
  return (u16)((u + 0x7fffu + ((u >> 16) & 1u)) >> 16);
}

// ---------------------------------------------------------------------------
// MFMA bf16 GEMM with f32 or bf16 operands (converted at LDS staging).
//   C[M,N] = A[M,K] @ W[N,K]^T + bias[N]  (+ epilogue)
// ADT : A dtype 0=f32, 1=bf16.  W,bias always f32 (from d_in).
// EPI : 0 none, 1 relu, 2 +residual.  RDT: residual dtype 0=f32, 1=bf16.
// OUTF: 1 bf16 out, 0 f32 out.   (round-6-proven, unchanged)
// ---------------------------------------------------------------------------
template<int ADT, int EPI, int RDT, int OUTF>
__global__ __launch_bounds__(256)
void gemm_mfma(const void* __restrict__ Av, const float* __restrict__ W,
               const float* __restrict__ bias, const void* __restrict__ Rv,
               void* __restrict__ Cout, int M, int N, int K)
{
  __shared__ u16 As[128 * 72];
  __shared__ u16 Bs[128 * 72];
  const int t = threadIdx.x;
  const int bm = blockIdx.y * 128, bn = blockIdx.x * 128;
  const int lane = t & 63, wave = t >> 6;
  const int lr = lane & 15, kg = lane >> 4;
  const int wr = wave >> 1, wc = wave & 1;
  const int srow = t >> 3, schk = (t & 7) * 8;

  f32x4 acc[4][4] = {};

  for (int k0 = 0; k0 < K; k0 += 64) {
#pragma unroll
    for (int p = 0; p < 4; p++) {
      const int r = srow + p * 32;
      s16x8 av = {};
      if (bm + r < M) {
        if (ADT == 0) {
          const float* ap = (const float*)Av + (size_t)(bm + r) * K + k0 + schk;
          const float4 a0 = *(const float4*)ap;
          const float4 a1 = *(const float4*)(ap + 4);
          av[0] = (short)f2b(a0.x); av[1] = (short)f2b(a0.y);
          av[2] = (short)f2b(a0.z); av[3] = (short)f2b(a0.w);
          av[4] = (short)f2b(a1.x); av[5] = (short)f2b(a1.y);
          av[6] = (short)f2b(a1.z); av[7] = (short)f2b(a1.w);
        } else {
          av = *(const s16x8*)((const u16*)Av + (size_t)(bm + r) * K + k0 + schk);
        }
      }
      *(s16x8*)&As[r * 72 + schk] = av;
      const float* wp = W + (size_t)(bn + r) * K + k0 + schk;  // N%128==0: in-range
      const float4 w0 = *(const float4*)wp;
      const float4 w1 = *(const float4*)(wp + 4);
      s16x8 wv;
      wv[0] = (short)f2b(w0.x); wv[1] = (short)f2b(w0.y);
      wv[2] = (short)f2b(w0.z); wv[3] = (short)f2b(w0.w);
      wv[4] = (short)f2b(w1.x); wv[5] = (short)f2b(w1.y);
      wv[6] = (short)f2b(w1.z); wv[7] = (short)f2b(w1.w);
      *(s16x8*)&Bs[r * 72 + schk] = wv;
    }
    __syncthreads();
#pragma unroll
    for (int ks = 0; ks < 2; ks++) {
      s16x8 af[4], bg[4];
#pragma unroll
      for (int m = 0; m < 4; m++)
        af[m] = *(const s16x8*)&As[(wr * 64 + m * 16 + lr) * 72 + ks * 32 + kg * 8];
#pragma unroll
      for (int n = 0; n < 4; n++)
        bg[n] = *(const s16x8*)&Bs[(wc * 64 + n * 16 + lr) * 72 + ks * 32 + kg * 8];
#pragma unroll
      for (int m = 0; m < 4; m++)
#pragma unroll
        for (int n = 0; n < 4; n++)
          acc[m][n] = __builtin_amdgcn_mfma_f32_16x16x32_bf16(af[m], bg[n], acc[m][n], 0, 0, 0);
    }
    __syncthreads();
  }

  float bv[4];
#pragma unroll
  for (int n = 0; n < 4; n++) bv[n] = bias[bn + wc * 64 + n * 16 + lr];
#pragma unroll
  for (int m = 0; m < 4; m++) {
#pragma unroll
    for (int j = 0; j < 4; j++) {
      const int row = bm + wr * 64 + m * 16 + kg * 4 + j;
      if (row >= M) continue;
#pragma unroll
      for (int n = 0; n < 4; n++) {
        const int col = bn + wc * 64 + n * 16 + lr;
        float x = acc[m][n][j] + bv[n];
        if (EPI == 1) x = fmaxf(x, 0.f);
        if (EPI == 2) {
          if (RDT == 0) x += ((const float*)Rv)[(size_t)row * N + col];
          else          x += b2f(((const u16*)Rv)[(size_t)row * N + col]);
        }
        if (OUTF) ((u16*)Cout)[(size_t)row * N + col] = f2b(x);
        else      ((float*)Cout)[(size_t)row * N + col] = x;
      }
    }
  }
}

// ---------------------------------------------------------------------------
// bf16 transpose: X (B*Lv, 512) -> Y (B, 512, Lvp) with zero-filled pad
// columns j in [Lv, Lvp). Lvp % 64 == 0 -> all attn V-loads 16B-aligned.
// ---------------------------------------------------------------------------
__global__ __launch_bounds__(256)
void transpose_k(const u16* __restrict__ X, u16* __restrict__ Y, int Lv, int Lvp)
{
  __shared__ u16 s[32][34];
  const int b = blockIdx.z, n0 = blockIdx.y * 32, j0 = blockIdx.x * 32;
  const int tx = threadIdx.x & 31, ty = threadIdx.x >> 5;
#pragma unroll
  for (int yy = 0; yy < 4; yy++) {
    const int j = j0 + ty + yy * 8;
    s[ty + yy * 8][tx] = (j < Lv) ? X[((size_t)b * Lv + j) * DM_ + n0 + tx] : (u16)0;
  }
  __syncthreads();
  const int j = j0 + tx;                       // j < Lvp by grid construction
#pragma unroll
  for (int yy = 0; yy < 4; yy++) {
    const int n = n0 + ty + yy * 8;
    Y[((size_t)b * DM_ + n) * Lvp + j] = s[tx][ty + yy * 8];
  }
}

// ---------------------------------------------------------------------------
// MFMA flash attention.  Block = 256 thr = 4 waves; each wave owns 16 q-rows
// of one (b,h); block covers 64 q-rows. KV loop in tiles of 64.
//   S^T = K.Q^T  (swapped operands: lane's q = lane&15 -> row-stats lane-local)
//   O^T = Vt.P   (same c-layout: softmax stats and O share lanes, no shuffles)
// P passes acc->B-frag through per-wave LDS (Plds) with a __syncthreads()
// between write and read: the un-barriered same-wave LDS RAW was the round-8
// warm-replay divergence suspect (only unprotected LDS RAW in the pipeline).
// Vt is padded to Lvp (%64==0): staging is 2 unconditional aligned loads.
// mask int32, index clamped (no speculative OOB). Finite sentinels only.
// ---------------------------------------------------------------------------
__global__ __launch_bounds__(256)
void attn_mfma(const u16* __restrict__ Q, const u16* __restrict__ K,
               const u16* __restrict__ Vt, const int* __restrict__ mask,
               u16* __restrict__ ctxb, int Lq, int Lv, int Lvp)
{
  __shared__ u16 Ks[64][72];       // K tile  [j][k]
  __shared__ u16 Vts[64][72];      // V^T tile [d][j]
  __shared__ u16 Plds[4][16][72];  // per-wave P / O bounce [q][j or d]
  const float SENT = -1e30f;
  const int qb = blockIdx.x, h = blockIdx.y, b = blockIdx.z;
  const int t = threadIdx.x, w = t >> 6, lane = t & 63;
  const int lr = lane & 15, g = lane >> 4;
  const int q0 = qb * 64 + w * 16;            // wave's q base
  const int myq = min(q0 + lr, Lq - 1);

  // Q fragment (B-operand of S^T): col=q, k from (lane>>4)*8
  s16x8 qf[2];
  const u16* qptr = Q + ((size_t)b * Lq + myq) * DM_ + h * 64;
#pragma unroll
  for (int ks = 0; ks < 2; ks++) qf[ks] = *(const s16x8*)(qptr + ks * 32 + g * 8);

  const int* mrow = mask + ((size_t)b * Lq + myq) * (size_t)Lv;

  f32x4 Ot[4] = {};
  float mx = SENT, l = 0.f;

  const int srow = t >> 2, sc16 = (t & 3) * 16;
  const u16* kbase  = K + (size_t)b * Lv * DM_ + h * 64;
  const u16* vtbase = Vt + ((size_t)b * DM_ + h * 64) * (size_t)Lvp;

  for (int j0 = 0; j0 < Lv; j0 += 64) {
    __syncthreads();                          // prev tile fully consumed
    {
      const int j = j0 + srow;
      if (j < Lv) {
        const u16* kp = kbase + (size_t)j * DM_ + sc16;
        *(s16x8*)&Ks[srow][sc16]     = *(const s16x8*)kp;
        *(s16x8*)&Ks[srow][sc16 + 8] = *(const s16x8*)(kp + 8);
      } else {
        const s16x8 z = {};
        *(s16x8*)&Ks[srow][sc16] = z; *(s16x8*)&Ks[srow][sc16 + 8] = z;
      }
      const u16* vp = vtbase + (size_t)srow * Lvp + j0 + sc16;  // aligned, in pad
      *(s16x8*)&Vts[srow][sc16]     = *(const s16x8*)vp;
      *(s16x8*)&Vts[srow][sc16 + 8] = *(const s16x8*)(vp + 8);
    }
    __syncthreads();

    // ---- S^T tile: Sa[m] rows j = m*16 + (lane>>4)*4 + reg, col q = lane&15
    f32x4 Sa[4] = {};
#pragma unroll
    for (int ks = 0; ks < 2; ks++) {
#pragma unroll
      for (int m = 0; m < 4; m++) {
        const s16x8 kf = *(const s16x8*)&Ks[m * 16 + lr][ks * 32 + g * 8];
        Sa[m] = __builtin_amdgcn_mfma_f32_16x16x32_bf16(kf, qf[ks], Sa[m], 0, 0, 0);
      }
    }

    // ---- mask + online softmax (lane holds 16 j-values for its q)
    float sv[4][4];
    float pm = SENT;
#pragma unroll
    for (int m = 0; m < 4; m++)
#pragma unroll
      for (int r = 0; r < 4; r++) {
        const int j = j0 + m * 16 + g * 4 + r;
        const int jc = min(j, Lv - 1);        // clamped: no OOB mask read
        float x = Sa[m][r] * 0.125f;
        x = ((j >= Lv) || (mrow[jc] != 0)) ? SENT : x;
        sv[m][r] = x;
        pm = fmaxf(pm, x);
      }
    pm = fmaxf(pm, __shfl_xor(pm, 16));
    pm = fmaxf(pm, __shfl_xor(pm, 32));       // column max over all 64 j
    float pr[4][4];
    if (pm > -1e29f) {
      const float mn = fmaxf(mx, pm);
      const float scale = __expf(mx - mn);    // mx=SENT -> 0, finite
      float ls = 0.f;
#pragma unroll
      for (int m = 0; m < 4; m++)
#pragma unroll
        for (int r = 0; r < 4; r++) {
          const float p = __expf(sv[m][r] - mn);
          pr[m][r] = p; ls += p;
        }
      ls += __shfl_xor(ls, 16);
      ls += __shfl_xor(ls, 32);
      l = l * scale + ls;
      mx = mn;
#pragma unroll
      for (int m = 0; m < 4; m++) Ot[m] *= scale;
    } else {
#pragma unroll
      for (int m = 0; m < 4; m++)
#pragma unroll
        for (int r = 0; r < 4; r++) pr[m][r] = 0.f;
    }

    // ---- P (bf16) -> Plds [q][j]
#pragma unroll
    for (int m = 0; m < 4; m++) {
      const unsigned lo = (unsigned)f2b(pr[m][0]) | ((unsigned)f2b(pr[m][1]) << 16);
      const unsigned hi = (unsigned)f2b(pr[m][2]) | ((unsigned)f2b(pr[m][3]) << 16);
      *(uint2*)&Plds[w][lr][m * 16 + g * 4] = make_uint2(lo, hi);
    }
    __syncthreads();   // FIX: force P-store completion before cross-lane read

    // ---- O^T += Vt-tile . P  (A=Vt rows d, B=P cols q)
#pragma unroll
    for (int ks = 0; ks < 2; ks++) {
#pragma unroll
      for (int m = 0; m < 4; m++) {
        const s16x8 vf = *(const s16x8*)&Vts[m * 16 + lr][ks * 32 + g * 8];
        const s16x8 pf = *(const s16x8*)&Plds[w][lr][ks * 32 + g * 8];
        Ot[m] = __builtin_amdgcn_mfma_f32_16x16x32_bf16(vf, pf, Ot[m], 0, 0, 0);
      }
    }
  }

  // ---- epilogue: normalize, bounce through Plds for coalesced bf16 store
  __syncthreads();                            // all PV reads of Plds done
  const float inv = l > 0.f ? 1.f / l : 0.f;
#pragma unroll
  for (int m = 0; m < 4; m++) {
    const unsigned lo = (unsigned)f2b(Ot[m][0] * inv) | ((unsigned)f2b(Ot[m][1] * inv) << 16);
    const unsigned hi = (unsigned)f2b(Ot[m][2] * inv) | ((unsigned)f2b(Ot[m][3] * inv) << 16);
    *(uint2*)&Plds[w][lr][m * 16 + g * 4] = make_uint2(lo, hi);
  }
  __syncthreads();                            // O-store complete before read
  const int oq = lane >> 2, od = (lane & 3) * 16;
  if (q0 + oq < Lq) {
    u16* op = ctxb + ((size_t)b * Lq + q0 + oq) * DM_ + h * 64 + od;
    *(s16x8*)op       = *(const s16x8*)&Plds[w][oq][od];
    *(s16x8*)(op + 8) = *(const s16x8*)&Plds[w][oq][od + 8];
  }
}

// ---------------------------------------------------------------------------
// Row LayerNorm (D=512, f32 in, f32 g/b) + non-pad mask (int32).
// OUTF: 1 bf16, 0 f32. In-place (Y==X) safe for OUTF=0.
// ---------------------------------------------------------------------------
template<int OUTF>
__global__ __launch_bounds__(256)
void ln_mask_kernel(const float* __restrict__ X, const float* __restrict__ g,
                    const float* __restrict__ bta, const int* __restrict__ npm,
                    void* __restrict__ Y)
{
  __shared__ float sm[8];
  const int row = blockIdx.x;
  const int t = threadIdx.x;
  const float2 x = *(const float2*)&X[(size_t)row * DM_ + t * 2];

  float s = x.x + x.y;
#pragma unroll
  for (int o = 32; o; o >>= 1) s += __shfl_xor(s, o);
  if ((t & 63) == 0) sm[t >> 6] = s;
  __syncthreads();
  const float mean = (sm[0] + sm[1] + sm[2] + sm[3]) * (1.f / DM_);

  const float d0 = x.x - mean, d1 = x.y - mean;
  float vs = d0 * d0 + d1 * d1;
#pragma unroll
  for (int o = 32; o; o >>= 1) vs += __shfl_xor(vs, o);
  if ((t & 63) == 0) sm[4 + (t >> 6)] = vs;
  __syncthreads();
  const float var = (sm[4] + sm[5] + sm[6] + sm[7]) * (1.f / DM_);

  const float inv = rsqrtf(var + 1e-5f);
  const float np = npm[row] ? 1.f : 0.f;
  const int c = t * 2;
  const float y0 = (d0 * inv * g[c]     + bta[c])     * np;
  const float y1 = (d1 * inv * g[c + 1] + bta[c + 1]) * np;
  if (OUTF) {
    const unsigned pair = (unsigned)f2b(y0) | ((unsigned)f2b(y1) << 16);
    *(unsigned*)((u16*)Y + (size_t)row * DM_ + c) = pair;
  } else {
    *(float2*)((float*)Y + (size_t)row * DM_ + c) = make_float2(y0, y1);
  }
}

// ---------------------------------------------------------------------------
// Gather valid rows (f32): out[i][:] = F[gather_idx[i]][:]
// ---------------------------------------------------------------------------
__global__ __launch_bounds__(128)
void gather_kernel(const float* __restrict__ F, const int* __restrict__ idx,
                   float* __restrict__ out)
{
  const int i = blockIdx.x;
  const int t = threadIdx.x;
  const int r = idx[i];
  *(float4*)&out[(size_t)i * DM_ + t * 4] =
      *(const float4*)&F[(size_t)r * DM_ + t * 4];
}

// ---------------------------------------------------------------------------
extern "C" void kernel_launch(void* const* d_in, const int* in_sizes, int n_in,
                              void* d_out, int out_size, void* d_ws, size_t ws_size,
                              hipStream_t stream)
{
  const float* entity = (const float*)d_in[0];
  const float* pred   = (const float*)d_in[1];
  const float* w_qs = (const float*)d_in[2];
  const float* b_qs = (const float*)d_in[3];
  const float* w_ks = (const float*)d_in[4];
  const float* b_ks = (const float*)d_in[5];
  const float* w_vs = (const float*)d_in[6];
  const float* b_vs = (const float*)d_in[7];
  const float* w_fc = (const float*)d_in[8];
  const float* b_fc = (const float*)d_in[9];
  const float* ln1g = (const float*)d_in[10];
  const float* ln1b = (const float*)d_in[11];
  const float* w1   = (const float*)d_in[12];
  const float* b1   = (const float*)d_in[13];
  const float* w2   = (const float*)d_in[14];
  const float* b2   = (const float*)d_in[15];
  const float* ln2g = (const float*)d_in[16];
  const float* ln2b = (const float*)d_in[17];
  const int* amask = (const int*)d_in[18];   // int32 bools
  const int* npm   = (const int*)d_in[19];   // int32 bools
  const int* gidx  = (const int*)d_in[20];

  const int Lq = in_sizes[0] / (B_ * DM_);
  const int Lv = in_sizes[1] / (B_ * DM_);
  const int Lvp = (Lv + 63) & ~63;           // padded V^T stride (16B-aligned rows)
  const int nValid = in_sizes[20];
  const int Mq = B_ * Lq, Mv = B_ * Lv;

  // Workspace: 5 regions, strict lifetime reuse (~73.5 MB; round-8: fits+ran)
  auto algn = [](size_t x) { return (x + 255) & ~(size_t)255; };
  const size_t bKV  = (size_t)Mv * DM_ * 2;   // bf16 K or V
  const size_t bVT  = (size_t)B_ * DM_ * Lvp * 2;  // bf16 V^T (padded)
  const size_t bTMP = (size_t)Mq * DM_ * 4;   // f32 tmp1/tmp2/ffin
  const size_t bH   = (size_t)Mq * DI_ * 2;   // bf16 FFN hidden
  const size_t bQ   = (size_t)Mq * DM_ * 2;   // bf16 Q / out1 / ctx
  const size_t szR1 = algn(bKV > bTMP ? bKV : bTMP);   // Kb -> tmp1 -> tmp2/ffin
  const size_t szR2 = algn(bKV > bH ? bKV : bH);       // Vb -> hb
  const size_t szR3 = algn(bQ);                        // Qb -> out1
  const size_t szR4 = algn(bQ);                        // ctxb
  const size_t szR5 = algn(bVT);                       // Vt
  if (szR1 + szR2 + szR3 + szR4 + szR5 > ws_size) return;  // tripwire (-> zeros)

  char* base = (char*)d_ws;
  char* R1 = base;
  char* R2 = R1 + szR1;
  char* R3 = R2 + szR2;
  char* R4 = R3 + szR3;
  char* R5 = R4 + szR4;

  u16*   Kb   = (u16*)R1;  float* tmp1 = (float*)R1;
  float* tmp2 = (float*)R1; float* ffin = (float*)R1;
  u16*   Vb   = (u16*)R2;  u16* hb = (u16*)R2;
  u16*   Qb   = (u16*)R3;  u16* out1 = (u16*)R3;
  u16*   ctxb = (u16*)R4;
  u16*   Vtb  = (u16*)R5;

  const dim3 blk(256);
  // Q/K/V projections: f32 A/W -> bf16 out (MFMA)
  gemm_mfma<0, 0, 0, 1><<<dim3(DM_ / 128, (Mq + 127) / 128), blk, 0, stream>>>(
      entity, w_qs, b_qs, nullptr, Qb, Mq, DM_, DM_);
  gemm_mfma<0, 0, 0, 1><<<dim3(DM_ / 128, (Mv + 127) / 128), blk, 0, stream>>>(
      pred, w_ks, b_ks, nullptr, Kb, Mv, DM_, DM_);
  gemm_mfma<0, 0, 0, 1><<<dim3(DM_ / 128, (Mv + 127) / 128), blk, 0, stream>>>(
      pred, w_vs, b_vs, nullptr, Vb, Mv, DM_, DM_);
  // V -> V^T (B, 512, Lvp), zero-padded
  transpose_k<<<dim3(Lvp / 32, DM_ / 32, B_), blk, 0, stream>>>(Vb, Vtb, Lv, Lvp);
  // MFMA flash attention
  attn_mfma<<<dim3((Lq + 63) / 64, H_, B_), blk, 0, stream>>>(
      Qb, Kb, Vtb, amask, ctxb, Lq, Lv, Lvp);
  // fc + residual(entity f32) -> f32 tmp1
  gemm_mfma<1, 2, 0, 0><<<dim3(DM_ / 128, (Mq + 127) / 128), blk, 0, stream>>>(
      ctxb, w_fc, b_fc, entity, tmp1, Mq, DM_, DM_);
  // LN1 + npm -> bf16 out1
  ln_mask_kernel<1><<<dim3(Mq), blk, 0, stream>>>(tmp1, ln1g, ln1b, npm, out1);
  // FFN1 (relu) -> bf16 hb
  gemm_mfma<1, 1, 0, 1><<<dim3(DI_ / 128, (Mq + 127) / 128), blk, 0, stream>>>(
      out1, w1, b1, nullptr, hb, Mq, DI_, DM_);
  // FFN2 + residual(out1 bf16) -> f32 tmp2
  gemm_mfma<1, 2, 1, 0><<<dim3(DM_ / 128, (Mq + 127) / 128), blk, 0, stream>>>(
      hb, w2, b2, out1, tmp2, Mq, DM_, DI_);
  // LN2 + npm -> f32 in-place (ffin == tmp2)
  ln_mask_kernel<0><<<dim3(Mq), blk, 0, stream>>>(tmp2, ln2g, ln2b, npm, ffin);
  // gather valid rows -> f32 d_out
  gather_kernel<<<dim3(nValid), dim3(128), 0, stream>>>(ffin, gidx, (float*)d_out);
}

// Round 12
// 440.684 us; speedup vs baseline: 3.1201x; 1.1639x over previous
//
#include <hip/hip_runtime.h>
#include <math.h>

#define B_  32
#define H_  8
#define DM_ 512
#define DI_ 2048

typedef unsigned short u16;
typedef short s16x8 __attribute__((ext_vector_type(8)));
typedef float f32x4 __attribute__((ext_vector_type(4)));

__device__ __forceinline__ float b2f(u16 u) {
  return __uint_as_float(((unsigned)u) << 16);
}
__device__ __forceinline__ u16 f2b(float f) {           // RNE f32 -> bf16
  unsigned u = __float_as_uint(f);
  return (u16)((u + 0x7fffu + ((u >> 16) & 1u)) >> 16);
}

// ---------------------------------------------------------------------------
// Batched f32 -> bf16 conversion: 8 segments, 4 elems/thread, grid-stride.
// All segment lengths are multiples of 4 (float4 / uint2 aligned).
// ---------------------------------------------------------------------------
struct CvtSeg { const float* src; u16* dst; unsigned n4; };
struct CvtArgs { CvtSeg s[8]; unsigned total4; };

__global__ __launch_bounds__(256)
void cvt_many(CvtArgs a)
{
  for (unsigned i = blockIdx.x * blockDim.x + threadIdx.x; i < a.total4;
       i += gridDim.x * blockDim.x) {
    unsigned r = i;
#pragma unroll
    for (int s = 0; s < 8; s++) {
      if (r < a.s[s].n4) {
        const float4 v = *(const float4*)(a.s[s].src + (size_t)r * 4);
        const unsigned lo = (unsigned)f2b(v.x) | ((unsigned)f2b(v.y) << 16);
        const unsigned hi = (unsigned)f2b(v.z) | ((unsigned)f2b(v.w) << 16);
        *(uint2*)(a.s[s].dst + (size_t)r * 4) = make_uint2(lo, hi);
        break;
      }
      r -= a.s[s].n4;
    }
  }
}

// ---------------------------------------------------------------------------
// Pure-bf16 MFMA GEMM: C[M,N] = A[M,K] @ W[N,K]^T + bias[N] (+ epilogue)
// EPI : 0 none, 1 relu, 2 +residual.  RDT: residual 0=f32, 1=bf16.
// OUTF: 1 bf16 out, 0 f32 out.  BIAS2: dual-bias KV mode (cols>=N/2 -> bias2).
// 128x128 tile, BK=64, 256 thr = 4 waves; staging = 1 b128 load + 1 b128
// LDS write per thread per p-iter (no conversion VALU in the hot loop).
// LDS [row][k] stride 72 u16. C/D: col=lane&15, row=(lane>>4)*4+reg.
// ---------------------------------------------------------------------------
template<int EPI, int RDT, int OUTF, int BIAS2>
__global__ __launch_bounds__(256)
void gemm_bf16(const u16* __restrict__ A, const u16* __restrict__ W,
               const float* __restrict__ bias, const float* __restrict__ bias2,
               const void* __restrict__ Rv, void* __restrict__ Cout,
               int M, int N, int K)
{
  __shared__ u16 As[128 * 72];
  __shared__ u16 Bs[128 * 72];
  const int t = threadIdx.x;
  const int bm = blockIdx.y * 128, bn = blockIdx.x * 128;
  const int lane = t & 63, wave = t >> 6;
  const int lr = lane & 15, kg = lane >> 4;
  const int wr = wave >> 1, wc = wave & 1;
  const int srow = t >> 3, schk = (t & 7) * 8;

  f32x4 acc[4][4] = {};

  for (int k0 = 0; k0 < K; k0 += 64) {
#pragma unroll
    for (int p = 0; p < 4; p++) {
      const int r = srow + p * 32;
      s16x8 av = {};
      if (bm + r < M) av = *(const s16x8*)&A[(size_t)(bm + r) * K + k0 + schk];
      *(s16x8*)&As[r * 72 + schk] = av;
      const s16x8 wv = *(const s16x8*)&W[(size_t)(bn + r) * K + k0 + schk];
      *(s16x8*)&Bs[r * 72 + schk] = wv;
    }
    __syncthreads();
#pragma unroll
    for (int ks = 0; ks < 2; ks++) {
      s16x8 af[4], bg[4];
#pragma unroll
      for (int m = 0; m < 4; m++)
        af[m] = *(const s16x8*)&As[(wr * 64 + m * 16 + lr) * 72 + ks * 32 + kg * 8];
#pragma unroll
      for (int n = 0; n < 4; n++)
        bg[n] = *(const s16x8*)&Bs[(wc * 64 + n * 16 + lr) * 72 + ks * 32 + kg * 8];
#pragma unroll
      for (int m = 0; m < 4; m++)
#pragma unroll
        for (int n = 0; n < 4; n++)
          acc[m][n] = __builtin_amdgcn_mfma_f32_16x16x32_bf16(af[m], bg[n], acc[m][n], 0, 0, 0);
    }
    __syncthreads();
  }

  const float* bp = bias;
  if (BIAS2) bp = (bn < (N >> 1)) ? bias : (bias2 - (N >> 1));
  float bv[4];
#pragma unroll
  for (int n = 0; n < 4; n++) bv[n] = bp[bn + wc * 64 + n * 16 + lr];
#pragma unroll
  for (int m = 0; m < 4; m++) {
#pragma unroll
    for (int j = 0; j < 4; j++) {
      const int row = bm + wr * 64 + m * 16 + kg * 4 + j;
      if (row >= M) continue;
#pragma unroll
      for (int n = 0; n < 4; n++) {
        const int col = bn + wc * 64 + n * 16 + lr;
        float x = acc[m][n][j] + bv[n];
        if (EPI == 1) x = fmaxf(x, 0.f);
        if (EPI == 2) {
          if (RDT == 0) x += ((const float*)Rv)[(size_t)row * N + col];
          else          x += b2f(((const u16*)Rv)[(size_t)row * N + col]);
        }
        if (OUTF) ((u16*)Cout)[(size_t)row * N + col] = f2b(x);
        else      ((float*)Cout)[(size_t)row * N + col] = x;
      }
    }
  }
}

// ---------------------------------------------------------------------------
// bf16 transpose of the V half of KV: X row j = KV[(b*Lv+j)*1024 + 512 + n]
// -> Y (B, 512, Lvp), zero-filled pad columns j in [Lv, Lvp). Lvp % 64 == 0.
// ---------------------------------------------------------------------------
__global__ __launch_bounds__(256)
void transpose_v(const u16* __restrict__ X, u16* __restrict__ Y, int Lv, int Lvp)
{
  __shared__ u16 s[32][34];
  const int b = blockIdx.z, n0 = blockIdx.y * 32, j0 = blockIdx.x * 32;
  const int tx = threadIdx.x & 31, ty = threadIdx.x >> 5;
#pragma unroll
  for (int yy = 0; yy < 4; yy++) {
    const int j = j0 + ty + yy * 8;
    s[ty + yy * 8][tx] =
        (j < Lv) ? X[((size_t)b * Lv + j) * 1024 + 512 + n0 + tx] : (u16)0;
  }
  __syncthreads();
  const int j = j0 + tx;                       // j < Lvp by grid construction
#pragma unroll
  for (int yy = 0; yy < 4; yy++) {
    const int n = n0 + ty + yy * 8;
    Y[((size_t)b * DM_ + n) * Lvp + j] = s[tx][ty + yy * 8];
  }
}

// ---------------------------------------------------------------------------
// MFMA flash attention (round-9-proven). K rows come from KV (stride 1024).
// Block = 4 waves; wave owns 16 q-rows of one (b,h). KV tiles of 64.
//   S^T = K.Q^T ; O^T = Vt.P. P bounces through per-wave LDS with barriers.
// ---------------------------------------------------------------------------
__global__ __launch_bounds__(256)
void attn_mfma(const u16* __restrict__ Q, const u16* __restrict__ KV,
               const u16* __restrict__ Vt, const int* __restrict__ mask,
               u16* __restrict__ ctxb, int Lq, int Lv, int Lvp)
{
  __shared__ u16 Ks[64][72];       // K tile  [j][k]
  __shared__ u16 Vts[64][72];      // V^T tile [d][j]
  __shared__ u16 Plds[4][16][72];  // per-wave P / O bounce
  const float SENT = -1e30f;
  const int qb = blockIdx.x, h = blockIdx.y, b = blockIdx.z;
  const int t = threadIdx.x, w = t >> 6, lane = t & 63;
  const int lr = lane & 15, g = lane >> 4;
  const int q0 = qb * 64 + w * 16;
  const int myq = min(q0 + lr, Lq - 1);

  s16x8 qf[2];
  const u16* qptr = Q + ((size_t)b * Lq + myq) * DM_ + h * 64;
#pragma unroll
  for (int ks = 0; ks < 2; ks++) qf[ks] = *(const s16x8*)(qptr + ks * 32 + g * 8);

  const int* mrow = mask + ((size_t)b * Lq + myq) * (size_t)Lv;

  f32x4 Ot[4] = {};
  float mx = SENT, l = 0.f;

  const int srow = t >> 2, sc16 = (t & 3) * 16;
  const u16* kbase  = KV + (size_t)b * Lv * 1024 + h * 64;      // stride 1024
  const u16* vtbase = Vt + ((size_t)b * DM_ + h * 64) * (size_t)Lvp;

  for (int j0 = 0; j0 < Lv; j0 += 64) {
    __syncthreads();
    {
      const int j = j0 + srow;
      if (j < Lv) {
        const u16* kp = kbase + (size_t)j * 1024 + sc16;
        *(s16x8*)&Ks[srow][sc16]     = *(const s16x8*)kp;
        *(s16x8*)&Ks[srow][sc16 + 8] = *(const s16x8*)(kp + 8);
      } else {
        const s16x8 z = {};
        *(s16x8*)&Ks[srow][sc16] = z; *(s16x8*)&Ks[srow][sc16 + 8] = z;
      }
      const u16* vp = vtbase + (size_t)srow * Lvp + j0 + sc16;
      *(s16x8*)&Vts[srow][sc16]     = *(const s16x8*)vp;
      *(s16x8*)&Vts[srow][sc16 + 8] = *(const s16x8*)(vp + 8);
    }
    __syncthreads();

    f32x4 Sa[4] = {};
#pragma unroll
    for (int ks = 0; ks < 2; ks++) {
#pragma unroll
      for (int m = 0; m < 4; m++) {
        const s16x8 kf = *(const s16x8*)&Ks[m * 16 + lr][ks * 32 + g * 8];
        Sa[m] = __builtin_amdgcn_mfma_f32_16x16x32_bf16(kf, qf[ks], Sa[m], 0, 0, 0);
      }
    }

    float sv[4][4];
    float pm = SENT;
#pragma unroll
    for (int m = 0; m < 4; m++)
#pragma unroll
      for (int r = 0; r < 4; r++) {
        const int j = j0 + m * 16 + g * 4 + r;
        const int jc = min(j, Lv - 1);
        float x = Sa[m][r] * 0.125f;
        x = ((j >= Lv) || (mrow[jc] != 0)) ? SENT : x;
        sv[m][r] = x;
        pm = fmaxf(pm, x);
      }
    pm = fmaxf(pm, __shfl_xor(pm, 16));
    pm = fmaxf(pm, __shfl_xor(pm, 32));
    float pr[4][4];
    if (pm > -1e29f) {
      const float mn = fmaxf(mx, pm);
      const float scale = __expf(mx - mn);
      float ls = 0.f;
#pragma unroll
      for (int m = 0; m < 4; m++)
#pragma unroll
        for (int r = 0; r < 4; r++) {
          const float p = __expf(sv[m][r] - mn);
          pr[m][r] = p; ls += p;
        }
      ls += __shfl_xor(ls, 16);
      ls += __shfl_xor(ls, 32);
      l = l * scale + ls;
      mx = mn;
#pragma unroll
      for (int m = 0; m < 4; m++) Ot[m] *= scale;
    } else {
#pragma unroll
      for (int m = 0; m < 4; m++)
#pragma unroll
        for (int r = 0; r < 4; r++) pr[m][r] = 0.f;
    }

#pragma unroll
    for (int m = 0; m < 4; m++) {
      const unsigned lo = (unsigned)f2b(pr[m][0]) | ((unsigned)f2b(pr[m][1]) << 16);
      const unsigned hi = (unsigned)f2b(pr[m][2]) | ((unsigned)f2b(pr[m][3]) << 16);
      *(uint2*)&Plds[w][lr][m * 16 + g * 4] = make_uint2(lo, hi);
    }
    __syncthreads();   // P-store complete before cross-lane read (r9 fix)

#pragma unroll
    for (int ks = 0; ks < 2; ks++) {
#pragma unroll
      for (int m = 0; m < 4; m++) {
        const s16x8 vf = *(const s16x8*)&Vts[m * 16 + lr][ks * 32 + g * 8];
        const s16x8 pf = *(const s16x8*)&Plds[w][lr][ks * 32 + g * 8];
        Ot[m] = __builtin_amdgcn_mfma_f32_16x16x32_bf16(vf, pf, Ot[m], 0, 0, 0);
      }
    }
  }

  __syncthreads();
  const float inv = l > 0.f ? 1.f / l : 0.f;
#pragma unroll
  for (int m = 0; m < 4; m++) {
    const unsigned lo = (unsigned)f2b(Ot[m][0] * inv) | ((unsigned)f2b(Ot[m][1] * inv) << 16);
    const unsigned hi = (unsigned)f2b(Ot[m][2] * inv) | ((unsigned)f2b(Ot[m][3] * inv) << 16);
    *(uint2*)&Plds[w][lr][m * 16 + g * 4] = make_uint2(lo, hi);
  }
  __syncthreads();
  const int oq = lane >> 2, od = (lane & 3) * 16;
  if (q0 + oq < Lq) {
    u16* op = ctxb + ((size_t)b * Lq + q0 + oq) * DM_ + h * 64 + od;
    *(s16x8*)op       = *(const s16x8*)&Plds[w][oq][od];
    *(s16x8*)(op + 8) = *(const s16x8*)&Plds[w][oq][od + 8];
  }
}

// ---------------------------------------------------------------------------
// Row LayerNorm (D=512, f32 in, f32 g/b) + non-pad mask (int32).
// OUTF: 1 bf16, 0 f32. In-place (Y==X) safe for OUTF=0.
// ---------------------------------------------------------------------------
template<int OUTF>
__global__ __launch_bounds__(256)
void ln_mask_kernel(const float* __restrict__ X, const float* __restrict__ g,
                    const float* __restrict__ bta, const int* __restrict__ npm,
                    void* __restrict__ Y)
{
  __shared__ float sm[8];
  const int row = blockIdx.x;
  const int t = threadIdx.x;
  const float2 x = *(const float2*)&X[(size_t)row * DM_ + t * 2];

  float s = x.x + x.y;
#pragma unroll
  for (int o = 32; o; o >>= 1) s += __shfl_xor(s, o);
  if ((t & 63) == 0) sm[t >> 6] = s;
  __syncthreads();
  const float mean = (sm[0] + sm[1] + sm[2] + sm[3]) * (1.f / DM_);

  const float d0 = x.x - mean, d1 = x.y - mean;
  float vs = d0 * d0 + d1 * d1;
#pragma unroll
  for (int o = 32; o; o >>= 1) vs += __shfl_xor(vs, o);
  if ((t & 63) == 0) sm[4 + (t >> 6)] = vs;
  __syncthreads();
  const float var = (sm[4] + sm[5] + sm[6] + sm[7]) * (1.f / DM_);

  const float inv = rsqrtf(var + 1e-5f);
  const float np = npm[row] ? 1.f : 0.f;
  const int c = t * 2;
  const float y0 = (d0 * inv * g[c]     + bta[c])     * np;
  const float y1 = (d1 * inv * g[c + 1] + bta[c + 1]) * np;
  if (OUTF) {
    const unsigned pair = (unsigned)f2b(y0) | ((unsigned)f2b(y1) << 16);
    *(unsigned*)((u16*)Y + (size_t)row * DM_ + c) = pair;
  } else {
    *(float2*)((float*)Y + (size_t)row * DM_ + c) = make_float2(y0, y1);
  }
}

// ---------------------------------------------------------------------------
// Gather valid rows (f32): out[i][:] = F[gather_idx[i]][:]
// ---------------------------------------------------------------------------
__global__ __launch_bounds__(128)
void gather_kernel(const float* __restrict__ F, const int* __restrict__ idx,
                   float* __restrict__ out)
{
  const int i = blockIdx.x;
  const int t = threadIdx.x;
  const int r = idx[i];
  *(float4*)&out[(size_t)i * DM_ + t * 4] =
      *(const float4*)&F[(size_t)r * DM_ + t * 4];
}

// ---------------------------------------------------------------------------
extern "C" void kernel_launch(void* const* d_in, const int* in_sizes, int n_in,
                              void* d_out, int out_size, void* d_ws, size_t ws_size,
                              hipStream_t stream)
{
  const float* entity = (const float*)d_in[0];
  const float* pred   = (const float*)d_in[1];
  const float* w_qs = (const float*)d_in[2];
  const float* b_qs = (const float*)d_in[3];
  const float* w_ks = (const float*)d_in[4];
  const float* b_ks = (const float*)d_in[5];
  const float* w_vs = (const float*)d_in[6];
  const float* b_vs = (const float*)d_in[7];
  const float* w_fc = (const float*)d_in[8];
  const float* b_fc = (const float*)d_in[9];
  const float* ln1g = (const float*)d_in[10];
  const float* ln1b = (const float*)d_in[11];
  const float* w1   = (const float*)d_in[12];
  const float* b1   = (const float*)d_in[13];
  const float* w2   = (const float*)d_in[14];
  const float* b2   = (const float*)d_in[15];
  const float* ln2g = (const float*)d_in[16];
  const float* ln2b = (const float*)d_in[17];
  const int* amask = (const int*)d_in[18];   // int32 bools
  const int* npm   = (const int*)d_in[19];   // int32 bools
  const int* gidx  = (const int*)d_in[20];

  const int Lq = in_sizes[0] / (B_ * DM_);
  const int Lv = in_sizes[1] / (B_ * DM_);
  const int Lvp = (Lv + 63) & ~63;
  const int nValid = in_sizes[20];
  const int Mq = B_ * Lq, Mv = B_ * Lv;

  // ------- workspace layout (lifetime-reused, ~77.5 MB) -------
  auto algn = [](size_t x) { return (x + 255) & ~(size_t)255; };
  const size_t bKV   = (size_t)Mv * 1024 * 2;          // fused K|V bf16
  const size_t bPred = (size_t)Mv * DM_ * 2;           // predB
  const size_t bVT   = (size_t)B_ * DM_ * Lvp * 2;     // Vt (padded)
  const size_t bTMP  = (size_t)Mq * DM_ * 4;           // f32 tmp
  const size_t bH    = (size_t)Mq * DI_ * 2;           // FFN hidden bf16
  const size_t bQ    = (size_t)Mq * DM_ * 2;           // Q / ctx / out1 bf16
  const size_t bW    = (size_t)(512 * 512 * 4 + 2048 * 512 * 2) * 2; // 3.15M u16

  const size_t szR1 = algn(bKV > algn(bTMP) + bH ? bKV : algn(bTMP) + bH);
  const size_t szR2 = algn(bPred > bVT ? bPred : bVT);
  const size_t szR3 = algn(bW);
  const size_t szR4 = algn(bQ);
  const size_t szR5 = algn(bQ);
  if (szR1 + szR2 + szR3 + szR4 + szR5 > ws_size) return;  // tripwire

  char* base = (char*)d_ws;
  char* R1 = base;
  char* R2 = R1 + szR1;
  char* R3 = R2 + szR2;
  char* R4 = R3 + szR3;
  char* R5 = R4 + szR4;

  u16*   KVb  = (u16*)R1;                       // steps 3-5
  float* tmp1 = (float*)R1;                     // steps 6-7
  u16*   hb   = (u16*)(R1 + algn(bTMP));        // steps 8-9
  float* tmp2 = (float*)R1;                     // steps 9-11 (tmp1 dead)
  float* ffin = tmp2;
  u16*   predB = (u16*)R2;                      // steps 1-3
  u16*   Vtb   = (u16*)R2;                      // steps 4-5 (predB dead)
  u16*   WB   = (u16*)R3;                       // steps 1-9
  u16*   entB = (u16*)R4;                       // steps 1-2
  u16*   ctxb = (u16*)R4;                       // steps 5-6 (entB dead)
  u16*   Qb   = (u16*)R5;                       // steps 2-5
  u16*   out1 = (u16*)R5;                       // steps 7-9 (Qb dead)

  // weight sub-buffers inside WB (u16 offsets)
  u16* WQ  = WB;                 // 512x512
  u16* WKV = WB + 262144;        // 1024x512 (w_ks rows 0-511, w_vs rows 512-1023)
  u16* WFC = WB + 786432;        // 512x512
  u16* W1  = WB + 1048576;       // 2048x512
  u16* W2  = WB + 2097152;       // 512x2048

  // ------- 1) batched f32->bf16 conversion -------
  CvtArgs ca;
  ca.s[0] = { entity, entB,          (unsigned)(Mq * DM_ / 4) };
  ca.s[1] = { pred,   predB,         (unsigned)(Mv * DM_ / 4) };
  ca.s[2] = { w_qs,   WQ,            262144 / 4 };
  ca.s[3] = { w_ks,   WKV,           262144 / 4 };
  ca.s[4] = { w_vs,   WKV + 262144,  262144 / 4 };
  ca.s[5] = { w_fc,   WFC,           262144 / 4 };
  ca.s[6] = { w1,     W1,            1048576 / 4 };
  ca.s[7] = { w2,     W2,            1048576 / 4 };
  ca.total4 = 0;
  for (int s = 0; s < 8; s++) ca.total4 += ca.s[s].n4;
  cvt_many<<<dim3(2048), dim3(256), 0, stream>>>(ca);

  const dim3 blk(256);
  // ------- 2) Q projection -------
  gemm_bf16<0, 0, 1, 0><<<dim3(DM_ / 128, (Mq + 127) / 128), blk, 0, stream>>>(
      entB, WQ, b_qs, nullptr, nullptr, Qb, Mq, DM_, DM_);
  // ------- 3) fused K|V projection (N=1024, dual bias) -------
  gemm_bf16<0, 0, 1, 1><<<dim3(1024 / 128, (Mv + 127) / 128), blk, 0, stream>>>(
      predB, WKV, b_ks, b_vs, nullptr, KVb, Mv, 1024, DM_);
  // ------- 4) V half -> V^T (B, 512, Lvp), zero-padded -------
  transpose_v<<<dim3(Lvp / 32, DM_ / 32, B_), blk, 0, stream>>>(KVb, Vtb, Lv, Lvp);
  // ------- 5) MFMA flash attention -------
  attn_mfma<<<dim3((Lq + 63) / 64, H_, B_), blk, 0, stream>>>(
      Qb, KVb, Vtb, amask, ctxb, Lq, Lv, Lvp);
  // ------- 6) fc + residual(entity f32) -> f32 tmp1 -------
  gemm_bf16<2, 0, 0, 0><<<dim3(DM_ / 128, (Mq + 127) / 128), blk, 0, stream>>>(
      ctxb, WFC, b_fc, nullptr, entity, tmp1, Mq, DM_, DM_);
  // ------- 7) LN1 + npm -> bf16 out1 -------
  ln_mask_kernel<1><<<dim3(Mq), blk, 0, stream>>>(tmp1, ln1g, ln1b, npm, out1);
  // ------- 8) FFN1 (relu) -> bf16 hb -------
  gemm_bf16<1, 0, 1, 0><<<dim3(DI_ / 128, (Mq + 127) / 128), blk, 0, stream>>>(
      out1, W1, b1, nullptr, nullptr, hb, Mq, DI_, DM_);
  // ------- 9) FFN2 + residual(out1 bf16) -> f32 tmp2 -------
  gemm_bf16<2, 1, 0, 0><<<dim3(DM_ / 128, (Mq + 127) / 128), blk, 0, stream>>>(
      hb, W2, b2, nullptr, out1, tmp2, Mq, DM_, DI_);
  // ------- 10) LN2 + npm -> f32 in-place -------
  ln_mask_kernel<0><<<dim3(Mq), blk, 0, stream>>>(tmp2, ln2g, ln2b, npm, ffin);
  // ------- 11) gather valid rows -> f32 d_out -------
  gather_kernel<<<dim3(nValid), dim3(128), 0, stream>>>(ffin, gidx, (float*)d_out);
}